// Round 13
// baseline (257.973 us; speedup 1.0000x reference)
//
#include <hip/hip_runtime.h>
#include <hip/hip_fp16.h>
#include <math.h>
#include <stdint.h>

#define NNZ_C 3200000
#define NN_C  100000
#define NE_C  100000
#define KD    16
#define EPSF  1e-6f
#define LSEP  0.1f

typedef unsigned int uint_t;

// ---------- workspace layout (word offsets), total ~9.8 MB ----------
//   [W_PK, +50000)   degree packed counters u32, 4x8-bit bins
//                    (node bins words [0,25000), edge bins [25000,50000))  (zeroed)
//   [W_ACC, +64)     acc: theta[0..15], fdvf[16..31], sep[32..35],
//                    done-counter in slot 63                               (zeroed)
//   [W_S, +1600000)  S edge-major fp32                                     (zeroed)
//   [W_NZ, +800000)  nZ fp16 (fully written by k_norm; 3.2 MB, L2-resident)
#define W_PK    0
#define W_ACC   50000
#define W_S     50064
#define W_NZ    (W_S + NE_C * KD)
#define W_END   (W_NZ + NN_C * KD / 2)
#define W_ZERO  W_NZ        // zero pk + acc + S (6.6 MB)

#define THETA_BLOCKS ((NE_C + 255) / 256)

// Native LDS float add (no memory clobber; ordering vs readers via __syncthreads)
__device__ __forceinline__ void lds_fadd(float* p, float v) {
    asm volatile("ds_add_f32 %0, %1"
                 :
                 : "v"((uint32_t)(uintptr_t)p), "v"(v));
}

// byte-extract a degree count from the packed histogram
__device__ __forceinline__ float deg_from_packed(const uint_t* __restrict__ packed,
                                                 int base_word, int idx) {
    uint_t w = packed[base_word + (idx >> 2)];
    return (float)((w >> ((idx & 3) * 8)) & 255u);
}

// ---- K1: degree histograms, ALL 100K bins per block (100 KB dynamic LDS) ---
// 128 blocks = 2 hists x 64 slices; each pin index is now read ONCE per hist
// (51.2 MB total vs 102.4 MB for the old 2-range version).
__global__ __launch_bounds__(512) void k_hist(const int* __restrict__ il,
                                              uint_t* __restrict__ packed) {
    extern __shared__ uint_t h[];            // 25000 words = 100 KB
    int t = threadIdx.x, b = blockIdx.x;
    int hist  = b >> 6;          // 0 -> node (Dv), 1 -> edge (De)
    int slice = b & 63;          // contiguous 50K-pin slice

    for (int w = t; w < 25000; w += 512) h[w] = 0u;
    __syncthreads();

    const int4* idx4 = (const int4*)(il + (size_t)hist * NNZ_C + (size_t)slice * 50000);
    for (int i = t; i < 12500; i += 512) {
        int4 v = idx4[i];
        uint_t u;
        u = (uint_t)v.x; atomicAdd(&h[u >> 2], 1u << ((u & 3u) * 8u));
        u = (uint_t)v.y; atomicAdd(&h[u >> 2], 1u << ((u & 3u) * 8u));
        u = (uint_t)v.z; atomicAdd(&h[u >> 2], 1u << ((u & 3u) * 8u));
        u = (uint_t)v.w; atomicAdd(&h[u >> 2], 1u << ((u & 3u) * 8u));
    }
    __syncthreads();

    uint_t* gp = packed + hist * 25000;
    for (int w = t; w < 25000; w += 512) {
        uint_t v = h[w];
        if (v) atomicAdd(&gp[w], v);         // coalesced line-RMWs
    }
}

// ---- K2: nZ(fp16) = Dv^-1/2 Z, f_Dv_f partials, separation stats -----------
__global__ __launch_bounds__(256) void k_norm(const float* __restrict__ Z,
                                              const uint_t* __restrict__ packed,
                                              __half* __restrict__ nZh,
                                              float* __restrict__ acc) {
    __shared__ float sacc[KD + 4];
    int t = threadIdx.x;
    if (t < KD + 4) sacc[t] = 0.f;
    __syncthreads();

    int n = blockIdx.x * 256 + t;
    if (n < NN_C) {
        float dv = fmaxf(deg_from_packed(packed, 0, n), EPSF);
        float inv = rsqrtf(dv);
        const float4* z4 = (const float4*)(Z + (size_t)n * KD);
        float zr[KD];
        #pragma unroll
        for (int i = 0; i < 4; ++i) {
            float4 z = z4[i];
            zr[4*i+0] = z.x; zr[4*i+1] = z.y; zr[4*i+2] = z.z; zr[4*i+3] = z.w;
        }
        uint4 u[2];
        __half2* hu = (__half2*)u;
        #pragma unroll
        for (int j = 0; j < 8; ++j)
            hu[j] = __floats2half2_rn(zr[2*j] * inv, zr[2*j+1] * inv);
        uint4* o = (uint4*)(nZh + (size_t)n * KD);
        o[0] = u[0];
        o[1] = u[1];
        #pragma unroll
        for (int k = 0; k < KD; ++k) lds_fadd(&sacc[k], zr[k] * zr[k] * dv);
        float f = zr[0];
        if (f > 0.f)      { lds_fadd(&sacc[KD+0], f); lds_fadd(&sacc[KD+2], 1.f); }
        else if (f < 0.f) { lds_fadd(&sacc[KD+1], f); lds_fadd(&sacc[KD+3], 1.f); }
    }
    __syncthreads();
    if (t < KD)          unsafeAtomicAdd(&acc[16 + t], sacc[t]);
    else if (t < KD + 4) unsafeAtomicAdd(&acc[32 + (t - KD)], sacc[t]);
}

// ---- K3: one-shot scatter, thread per (pin,k) -------------------------------
// 3.2M 64B-line RMWs at the measured ~20 G lines/s device atomic rate: this
// IS the wall (163 us); replication (r11) and aggregation (r4-r10) don't beat it.
__global__ __launch_bounds__(256) void k_scatter(const int* __restrict__ il,
                                                 const __half* __restrict__ nZh,
                                                 float* __restrict__ S) {
    uint_t tid = blockIdx.x * 256u + threadIdx.x;
    if (tid < (uint_t)NNZ_C * KD) {
        uint_t p = tid >> 4, k = tid & 15u;
        int n = il[p];
        int e = il[NNZ_C + p];
        float v = __half2float(nZh[(size_t)n * KD + k]);
        unsafeAtomicAdd(&S[(size_t)e * KD + k], v);
    }
}

// ---- K4: theta + fused last-block finalize ----------------------------------
__global__ __launch_bounds__(256) void k_theta(const float* __restrict__ S,
                                               const uint_t* __restrict__ packed,
                                               float* __restrict__ acc,
                                               float* __restrict__ out) {
    __shared__ float sacc[KD];
    __shared__ uint_t lastflag;
    int t = threadIdx.x;
    if (t < KD) sacc[t] = 0.f;
    __syncthreads();
    int e = blockIdx.x * 256 + t;
    if (e < NE_C) {
        float rinv = 1.f / fmaxf(deg_from_packed(packed, 25000, e), EPSF);
        const float4* s4 = (const float4*)(S + (size_t)e * KD);
        #pragma unroll
        for (int i = 0; i < 4; ++i) {
            float4 s = s4[i];
            lds_fadd(&sacc[4*i+0], s.x * s.x * rinv);
            lds_fadd(&sacc[4*i+1], s.y * s.y * rinv);
            lds_fadd(&sacc[4*i+2], s.z * s.z * rinv);
            lds_fadd(&sacc[4*i+3], s.w * s.w * rinv);
        }
    }
    __syncthreads();
    if (t < KD) unsafeAtomicAdd(&acc[t], sacc[t]);

    // last block to finish finalizes the scalar loss (saves the k_final launch)
    __threadfence();
    if (t == 0) {
        uint_t old = atomicAdd((uint_t*)(acc + 63), 1u);
        lastflag = (old == (uint_t)(THETA_BLOCKS - 1));
    }
    __syncthreads();
    if (lastflag && t == 0) {
        float a[36];
        #pragma unroll
        for (int i = 0; i < 36; ++i) a[i] = unsafeAtomicAdd(&acc[i], 0.f);  // coherent read
        float rsum = 0.f;
        #pragma unroll
        for (int k = 0; k < KD; ++k) {
            float theta = a[k];
            float fd    = fmaxf(a[16 + k], EPSF);
            float rq    = 1.f - theta / fd;
            if (!isfinite(rq)) rq = 0.f;
            rsum += rq;
        }
        float rl = rsum / (float)KD;
        float pS = a[32], nS = a[33], pC = a[34], nC = a[35];
        float pm = pS / fmaxf(pC, 1.f);
        float nm = nS / fmaxf(nC, 1.f);
        float sep = fabsf(pm - nm);
        float pen = (pC == 0.f || nC == 0.f) ? 1.f : 1.f / (sep + EPSF);
        out[0] = rl + LSEP * pen;
    }
}

extern "C" void kernel_launch(void* const* d_in, const int* in_sizes, int n_in,
                              void* d_out, int out_size, void* d_ws, size_t ws_size,
                              hipStream_t stream) {
    const float* Z  = (const float*)d_in[0];
    const int*   il = (const int*)d_in[1];   // (2, NNZ) int32
    float*  ws     = (float*)d_ws;
    uint_t* packed = (uint_t*)d_ws + W_PK;
    float*  acc    = ws + W_ACC;
    float*  S      = ws + W_S;
    __half* nZh    = (__half*)(ws + W_NZ);
    float*  out    = (float*)d_out;

    // zero pk + acc(+done counter) + S every call (scatter accumulates with +=)
    hipMemsetAsync(ws, 0, (size_t)W_ZERO * sizeof(float), stream);

    k_hist <<<128, 512, 100000, stream>>>(il, packed);
    k_norm <<<(NN_C + 255) / 256, 256, 0, stream>>>(Z, packed, nZh, acc);
    {
        uint_t total = (uint_t)NNZ_C * KD;
        k_scatter<<<(total + 255) / 256, 256, 0, stream>>>(il, nZh, S);
    }
    k_theta<<<THETA_BLOCKS, 256, 0, stream>>>(S, packed, acc, out);
}

// Round 14
// 257.665 us; speedup vs baseline: 1.0012x; 1.0012x over previous
//
#include <hip/hip_runtime.h>
#include <hip/hip_fp16.h>
#include <math.h>
#include <stdint.h>

#define NNZ_C 3200000
#define NN_C  100000
#define NE_C  100000
#define KD    16
#define EPSF  1e-6f
#define LSEP  0.1f

typedef unsigned int uint_t;

// ---------- workspace layout (word offsets), total ~9.8 MB ----------
//   [W_PK, +50000)   degree packed counters u32, 4x8-bit bins
//                    (node bins words [0,25000), edge bins [25000,50000))  (zeroed)
//   [W_ACC, +64)     acc: theta[0..15], fdvf[16..31], sep[32..35],
//                    done-counter in slot 63                               (zeroed)
//   [W_S, +1600000)  S edge-major fp32                                     (zeroed)
//   [W_NZ, +800000)  nZ fp16 (fully written by k_norm; 3.2 MB, L2-resident)
#define W_PK    0
#define W_ACC   50000
#define W_S     50064
#define W_NZ    (W_S + NE_C * KD)
#define W_END   (W_NZ + NN_C * KD / 2)
#define W_ZERO  W_NZ        // zero pk + acc + S (6.6 MB)

#define THETA_BLOCKS ((NE_C + 255) / 256)

// Native LDS float add (no memory clobber; ordering vs readers via __syncthreads)
__device__ __forceinline__ void lds_fadd(float* p, float v) {
    asm volatile("ds_add_f32 %0, %1"
                 :
                 : "v"((uint32_t)(uintptr_t)p), "v"(v));
}

// byte-extract a degree count from the packed histogram
__device__ __forceinline__ float deg_from_packed(const uint_t* __restrict__ packed,
                                                 int base_word, int idx) {
    uint_t w = packed[base_word + (idx >> 2)];
    return (float)((w >> ((idx & 3) * 8)) & 255u);
}

// ---- K1: degree histograms (node + edge), LDS byte-packed, r12 config ------
// 256 blocks x 512 thr (50 KB static LDS -> >=2 blocks/CU, all CUs busy).
// Each of 2 hists x 2 bin-ranges re-reads its pin row (102 MB total): r13
// proved the single-read 100KB-LDS variant loses more to 128-block
// underoccupancy than it saves in traffic.
__global__ __launch_bounds__(512) void k_hist(const int* __restrict__ il,
                                              uint_t* __restrict__ packed) {
    __shared__ uint_t h[12500];
    int t = threadIdx.x, b = blockIdx.x;
    int hist  = b >> 7;          // 0 -> node (Dv), 1 -> edge (De)
    int range = (b >> 6) & 1;    // bins [range*50000, +50000)
    int slice = b & 63;          // contiguous 50K-pin slice

    for (int w = t; w < 12500; w += 512) h[w] = 0u;
    __syncthreads();

    const int4* idx4 = (const int4*)(il + (size_t)hist * NNZ_C + (size_t)slice * 50000);
    uint_t base = (uint_t)range * 50000u;
    for (int i = t; i < 12500; i += 512) {
        int4 v = idx4[i];
        uint_t u;
        u = (uint_t)v.x - base; if (u < 50000u) atomicAdd(&h[u >> 2], 1u << ((u & 3u) * 8u));
        u = (uint_t)v.y - base; if (u < 50000u) atomicAdd(&h[u >> 2], 1u << ((u & 3u) * 8u));
        u = (uint_t)v.z - base; if (u < 50000u) atomicAdd(&h[u >> 2], 1u << ((u & 3u) * 8u));
        u = (uint_t)v.w - base; if (u < 50000u) atomicAdd(&h[u >> 2], 1u << ((u & 3u) * 8u));
    }
    __syncthreads();

    uint_t* gp = packed + hist * 25000 + range * 12500;
    for (int w = t; w < 12500; w += 512) {
        uint_t v = h[w];
        if (v) atomicAdd(&gp[w], v);
    }
}

// ---- K2: nZ(fp16) = Dv^-1/2 Z, f_Dv_f partials, separation stats -----------
__global__ __launch_bounds__(256) void k_norm(const float* __restrict__ Z,
                                              const uint_t* __restrict__ packed,
                                              __half* __restrict__ nZh,
                                              float* __restrict__ acc) {
    __shared__ float sacc[KD + 4];
    int t = threadIdx.x;
    if (t < KD + 4) sacc[t] = 0.f;
    __syncthreads();

    int n = blockIdx.x * 256 + t;
    if (n < NN_C) {
        float dv = fmaxf(deg_from_packed(packed, 0, n), EPSF);
        float inv = rsqrtf(dv);
        const float4* z4 = (const float4*)(Z + (size_t)n * KD);
        float zr[KD];
        #pragma unroll
        for (int i = 0; i < 4; ++i) {
            float4 z = z4[i];
            zr[4*i+0] = z.x; zr[4*i+1] = z.y; zr[4*i+2] = z.z; zr[4*i+3] = z.w;
        }
        uint4 u[2];
        __half2* hu = (__half2*)u;
        #pragma unroll
        for (int j = 0; j < 8; ++j)
            hu[j] = __floats2half2_rn(zr[2*j] * inv, zr[2*j+1] * inv);
        uint4* o = (uint4*)(nZh + (size_t)n * KD);
        o[0] = u[0];
        o[1] = u[1];
        #pragma unroll
        for (int k = 0; k < KD; ++k) lds_fadd(&sacc[k], zr[k] * zr[k] * dv);
        float f = zr[0];
        if (f > 0.f)      { lds_fadd(&sacc[KD+0], f); lds_fadd(&sacc[KD+2], 1.f); }
        else if (f < 0.f) { lds_fadd(&sacc[KD+1], f); lds_fadd(&sacc[KD+3], 1.f); }
    }
    __syncthreads();
    if (t < KD)          unsafeAtomicAdd(&acc[16 + t], sacc[t]);
    else if (t < KD + 4) unsafeAtomicAdd(&acc[32 + (t - KD)], sacc[t]);
}

// ---- K3: one-shot scatter, thread per (pin,k) -------------------------------
// 3.2M 64B-line RMWs at the measured ~20 G lines/s device atomic rate: this
// IS the wall (163 us, stable r3/r11/r12/r13). Replication (r11), LDS
// aggregation (r4-r9), and payload-width arithmetic all fail to beat it.
__global__ __launch_bounds__(256) void k_scatter(const int* __restrict__ il,
                                                 const __half* __restrict__ nZh,
                                                 float* __restrict__ S) {
    uint_t tid = blockIdx.x * 256u + threadIdx.x;
    if (tid < (uint_t)NNZ_C * KD) {
        uint_t p = tid >> 4, k = tid & 15u;
        int n = il[p];
        int e = il[NNZ_C + p];
        float v = __half2float(nZh[(size_t)n * KD + k]);
        unsafeAtomicAdd(&S[(size_t)e * KD + k], v);
    }
}

// ---- K4: theta + fused last-block finalize ----------------------------------
__global__ __launch_bounds__(256) void k_theta(const float* __restrict__ S,
                                               const uint_t* __restrict__ packed,
                                               float* __restrict__ acc,
                                               float* __restrict__ out) {
    __shared__ float sacc[KD];
    __shared__ uint_t lastflag;
    int t = threadIdx.x;
    if (t < KD) sacc[t] = 0.f;
    __syncthreads();
    int e = blockIdx.x * 256 + t;
    if (e < NE_C) {
        float rinv = 1.f / fmaxf(deg_from_packed(packed, 25000, e), EPSF);
        const float4* s4 = (const float4*)(S + (size_t)e * KD);
        #pragma unroll
        for (int i = 0; i < 4; ++i) {
            float4 s = s4[i];
            lds_fadd(&sacc[4*i+0], s.x * s.x * rinv);
            lds_fadd(&sacc[4*i+1], s.y * s.y * rinv);
            lds_fadd(&sacc[4*i+2], s.z * s.z * rinv);
            lds_fadd(&sacc[4*i+3], s.w * s.w * rinv);
        }
    }
    __syncthreads();
    if (t < KD) unsafeAtomicAdd(&acc[t], sacc[t]);

    // last block to finish finalizes the scalar loss (saves the k_final launch)
    __threadfence();
    if (t == 0) {
        uint_t old = atomicAdd((uint_t*)(acc + 63), 1u);
        lastflag = (old == (uint_t)(THETA_BLOCKS - 1));
    }
    __syncthreads();
    if (lastflag && t == 0) {
        float a[36];
        #pragma unroll
        for (int i = 0; i < 36; ++i) a[i] = unsafeAtomicAdd(&acc[i], 0.f);  // coherent read
        float rsum = 0.f;
        #pragma unroll
        for (int k = 0; k < KD; ++k) {
            float theta = a[k];
            float fd    = fmaxf(a[16 + k], EPSF);
            float rq    = 1.f - theta / fd;
            if (!isfinite(rq)) rq = 0.f;
            rsum += rq;
        }
        float rl = rsum / (float)KD;
        float pS = a[32], nS = a[33], pC = a[34], nC = a[35];
        float pm = pS / fmaxf(pC, 1.f);
        float nm = nS / fmaxf(nC, 1.f);
        float sep = fabsf(pm - nm);
        float pen = (pC == 0.f || nC == 0.f) ? 1.f : 1.f / (sep + EPSF);
        out[0] = rl + LSEP * pen;
    }
}

extern "C" void kernel_launch(void* const* d_in, const int* in_sizes, int n_in,
                              void* d_out, int out_size, void* d_ws, size_t ws_size,
                              hipStream_t stream) {
    const float* Z  = (const float*)d_in[0];
    const int*   il = (const int*)d_in[1];   // (2, NNZ) int32
    float*  ws     = (float*)d_ws;
    uint_t* packed = (uint_t*)d_ws + W_PK;
    float*  acc    = ws + W_ACC;
    float*  S      = ws + W_S;
    __half* nZh    = (__half*)(ws + W_NZ);
    float*  out    = (float*)d_out;

    // zero pk + acc(+done counter) + S every call (scatter accumulates with +=)
    hipMemsetAsync(ws, 0, (size_t)W_ZERO * sizeof(float), stream);

    k_hist <<<256, 512, 0, stream>>>(il, packed);
    k_norm <<<(NN_C + 255) / 256, 256, 0, stream>>>(Z, packed, nZh, acc);
    {
        uint_t total = (uint_t)NNZ_C * KD;
        k_scatter<<<(total + 255) / 256, 256, 0, stream>>>(il, nZh, S);
    }
    k_theta<<<THETA_BLOCKS, 256, 0, stream>>>(S, packed, acc, out);
}

// Round 15
// 232.332 us; speedup vs baseline: 1.1104x; 1.1090x over previous
//
#include <hip/hip_runtime.h>
#include <hip/hip_fp16.h>
#include <math.h>
#include <stdint.h>

#define NNZ_C 3200000
#define NN_C  100000
#define NE_C  100000
#define KD    16
#define EPSF  1e-6f
#define LSEP  0.1f

typedef unsigned int uint_t;

// ---------- workspace layout (word offsets), total ~9.8 MB ----------
//   [W_PK, +50000)   degree packed counters u32, 4x8-bit bins
//                    (node bins words [0,25000), edge bins [25000,50000))  (zeroed)
//   [W_ACC, +64)     acc: theta[0..15], fdvf[16..31], sep[32..35]          (zeroed)
//   [W_S, +1600000)  S edge-major fp32                                     (zeroed)
//   [W_NZ, +800000)  nZ fp16 (fully written by k_norm; 3.2 MB, L2-resident)
#define W_PK    0
#define W_ACC   50000
#define W_S     50064
#define W_NZ    (W_S + NE_C * KD)
#define W_END   (W_NZ + NN_C * KD / 2)
#define W_ZERO  W_NZ        // zero pk + acc + S (6.6 MB)

// Native LDS float add (no memory clobber; ordering vs readers via __syncthreads)
__device__ __forceinline__ void lds_fadd(float* p, float v) {
    asm volatile("ds_add_f32 %0, %1"
                 :
                 : "v"((uint32_t)(uintptr_t)p), "v"(v));
}

// byte-extract a degree count from the packed histogram
__device__ __forceinline__ float deg_from_packed(const uint_t* __restrict__ packed,
                                                 int base_word, int idx) {
    uint_t w = packed[base_word + (idx >> 2)];
    return (float)((w >> ((idx & 3) * 8)) & 255u);
}

// ---- K1: degree histograms (node + edge), LDS byte-packed ------------------
// 256 blocks x 512 thr, 50 KB static LDS. (r13's single-pass 100KB variant and
// r13/r14's fused finalize both measured as regressions; this is the r12 best.)
__global__ __launch_bounds__(512) void k_hist(const int* __restrict__ il,
                                              uint_t* __restrict__ packed) {
    __shared__ uint_t h[12500];
    int t = threadIdx.x, b = blockIdx.x;
    int hist  = b >> 7;          // 0 -> node (Dv), 1 -> edge (De)
    int range = (b >> 6) & 1;    // bins [range*50000, +50000)
    int slice = b & 63;          // contiguous 50K-pin slice

    for (int w = t; w < 12500; w += 512) h[w] = 0u;
    __syncthreads();

    const int4* idx4 = (const int4*)(il + (size_t)hist * NNZ_C + (size_t)slice * 50000);
    uint_t base = (uint_t)range * 50000u;
    for (int i = t; i < 12500; i += 512) {
        int4 v = idx4[i];
        uint_t u;
        u = (uint_t)v.x - base; if (u < 50000u) atomicAdd(&h[u >> 2], 1u << ((u & 3u) * 8u));
        u = (uint_t)v.y - base; if (u < 50000u) atomicAdd(&h[u >> 2], 1u << ((u & 3u) * 8u));
        u = (uint_t)v.z - base; if (u < 50000u) atomicAdd(&h[u >> 2], 1u << ((u & 3u) * 8u));
        u = (uint_t)v.w - base; if (u < 50000u) atomicAdd(&h[u >> 2], 1u << ((u & 3u) * 8u));
    }
    __syncthreads();

    uint_t* gp = packed + hist * 25000 + range * 12500;
    for (int w = t; w < 12500; w += 512) {
        uint_t v = h[w];
        if (v) atomicAdd(&gp[w], v);
    }
}

// ---- K2: nZ(fp16) = Dv^-1/2 Z, f_Dv_f partials, separation stats -----------
__global__ __launch_bounds__(256) void k_norm(const float* __restrict__ Z,
                                              const uint_t* __restrict__ packed,
                                              __half* __restrict__ nZh,
                                              float* __restrict__ acc) {
    __shared__ float sacc[KD + 4];
    int t = threadIdx.x;
    if (t < KD + 4) sacc[t] = 0.f;
    __syncthreads();

    int n = blockIdx.x * 256 + t;
    if (n < NN_C) {
        float dv = fmaxf(deg_from_packed(packed, 0, n), EPSF);
        float inv = rsqrtf(dv);
        const float4* z4 = (const float4*)(Z + (size_t)n * KD);
        float zr[KD];
        #pragma unroll
        for (int i = 0; i < 4; ++i) {
            float4 z = z4[i];
            zr[4*i+0] = z.x; zr[4*i+1] = z.y; zr[4*i+2] = z.z; zr[4*i+3] = z.w;
        }
        uint4 u[2];
        __half2* hu = (__half2*)u;
        #pragma unroll
        for (int j = 0; j < 8; ++j)
            hu[j] = __floats2half2_rn(zr[2*j] * inv, zr[2*j+1] * inv);
        uint4* o = (uint4*)(nZh + (size_t)n * KD);
        o[0] = u[0];
        o[1] = u[1];
        #pragma unroll
        for (int k = 0; k < KD; ++k) lds_fadd(&sacc[k], zr[k] * zr[k] * dv);
        float f = zr[0];
        if (f > 0.f)      { lds_fadd(&sacc[KD+0], f); lds_fadd(&sacc[KD+2], 1.f); }
        else if (f < 0.f) { lds_fadd(&sacc[KD+1], f); lds_fadd(&sacc[KD+3], 1.f); }
    }
    __syncthreads();
    if (t < KD)          unsafeAtomicAdd(&acc[16 + t], sacc[t]);
    else if (t < KD + 4) unsafeAtomicAdd(&acc[32 + (t - KD)], sacc[t]);
}

// ---- K3: one-shot scatter, thread per (pin,k) -------------------------------
// 3.2M 64B-line RMWs at the measured ~20 G lines/s device atomic rate: this
// IS the wall (163 us, invariant r3/r11-r14). Replication (r11), LDS
// aggregation (r4-r9), native-vs-CAS (r10), payload width (arithmetic) all
// fail to beat it.
__global__ __launch_bounds__(256) void k_scatter(const int* __restrict__ il,
                                                 const __half* __restrict__ nZh,
                                                 float* __restrict__ S) {
    uint_t tid = blockIdx.x * 256u + threadIdx.x;
    if (tid < (uint_t)NNZ_C * KD) {
        uint_t p = tid >> 4, k = tid & 15u;
        int n = il[p];
        int e = il[NNZ_C + p];
        float v = __half2float(nZh[(size_t)n * KD + k]);
        unsafeAtomicAdd(&S[(size_t)e * KD + k], v);
    }
}

// ---- K4: theta[k] = sum_e S[e,k]^2 / De[e] ----------------------------------
__global__ __launch_bounds__(256) void k_theta(const float* __restrict__ S,
                                               const uint_t* __restrict__ packed,
                                               float* __restrict__ acc) {
    __shared__ float sacc[KD];
    int t = threadIdx.x;
    if (t < KD) sacc[t] = 0.f;
    __syncthreads();
    int e = blockIdx.x * 256 + t;
    if (e < NE_C) {
        float rinv = 1.f / fmaxf(deg_from_packed(packed, 25000, e), EPSF);
        const float4* s4 = (const float4*)(S + (size_t)e * KD);
        #pragma unroll
        for (int i = 0; i < 4; ++i) {
            float4 s = s4[i];
            lds_fadd(&sacc[4*i+0], s.x * s.x * rinv);
            lds_fadd(&sacc[4*i+1], s.y * s.y * rinv);
            lds_fadd(&sacc[4*i+2], s.z * s.z * rinv);
            lds_fadd(&sacc[4*i+3], s.w * s.w * rinv);
        }
    }
    __syncthreads();
    if (t < KD) unsafeAtomicAdd(&acc[t], sacc[t]);
}

// ---- K5: finalize (separate launch: r13/r14 proved in-kernel fusion via
// __threadfence costs ~25 us vs ~2 us for this launch) -------------------------
__global__ void k_final(const float* __restrict__ acc, float* __restrict__ out) {
    if (blockIdx.x == 0 && threadIdx.x == 0) {
        float rsum = 0.f;
        #pragma unroll
        for (int k = 0; k < KD; ++k) {
            float theta = acc[k];
            float fd    = fmaxf(acc[16 + k], EPSF);
            float rq    = 1.f - theta / fd;
            if (!isfinite(rq)) rq = 0.f;
            rsum += rq;
        }
        float rl = rsum / (float)KD;
        float pS = acc[32], nS = acc[33], pC = acc[34], nC = acc[35];
        float pm = pS / fmaxf(pC, 1.f);
        float nm = nS / fmaxf(nC, 1.f);
        float sep = fabsf(pm - nm);
        float pen = (pC == 0.f || nC == 0.f) ? 1.f : 1.f / (sep + EPSF);
        out[0] = rl + LSEP * pen;
    }
}

extern "C" void kernel_launch(void* const* d_in, const int* in_sizes, int n_in,
                              void* d_out, int out_size, void* d_ws, size_t ws_size,
                              hipStream_t stream) {
    const float* Z  = (const float*)d_in[0];
    const int*   il = (const int*)d_in[1];   // (2, NNZ) int32
    float*  ws     = (float*)d_ws;
    uint_t* packed = (uint_t*)d_ws + W_PK;
    float*  acc    = ws + W_ACC;
    float*  S      = ws + W_S;
    __half* nZh    = (__half*)(ws + W_NZ);
    float*  out    = (float*)d_out;

    // zero packed + acc + S every call (scatter accumulates with +=)
    hipMemsetAsync(ws, 0, (size_t)W_ZERO * sizeof(float), stream);

    k_hist  <<<256, 512, 0, stream>>>(il, packed);
    k_norm  <<<(NN_C + 255) / 256, 256, 0, stream>>>(Z, packed, nZh, acc);
    {
        uint_t total = (uint_t)NNZ_C * KD;
        k_scatter<<<(total + 255) / 256, 256, 0, stream>>>(il, nZh, S);
    }
    k_theta <<<(NE_C + 255) / 256, 256, 0, stream>>>(S, packed, acc);
    k_final <<<1, 64, 0, stream>>>(acc, out);
}